// Round 7
// baseline (120.544 us; speedup 1.0000x reference)
//
#include <hip/hip_runtime.h>
#include <hip/hip_bf16.h>
#include <hip/hip_fp16.h>

#define Bdim 256
#define Sdim 196
#define Hdim 1024
#define Fdim 2048
#define BH (Bdim*Hdim)      // 262144
#define L2E 1.44269504f
#define C2L 2.88539008f     // 2*log2(e)

typedef float nfloat4 __attribute__((ext_vector_type(4)));

__device__ __forceinline__ float4 ldnt4(const float* p) {
    nfloat4 v = __builtin_nontemporal_load(reinterpret_cast<const nfloat4*>(p));
    return make_float4(v.x, v.y, v.z, v.w);
}

// ---------------- Kernel A: qpart(fp16) = slices of ha@W_ha^T + hf@W_hf^T -------
// TM=128 x TN=128, TK=32; 256 threads, micro 8x8; K-split KS=32 (kchunk=64)
#define TM 128
#define TN 128
#define TK 32

__global__ __launch_bounds__(256) void gemm_q_part(
    const float* __restrict__ ha, const float* __restrict__ hf,
    const float* __restrict__ Wha, const float* __restrict__ Whf,
    __half* __restrict__ qpart, int kchunk)
{
    __shared__ float As[TK][TM + 4];
    __shared__ float Ws[TK][TN + 4];

    const int tid = threadIdx.x;
    const int th  = tid & 15;          // h-group: 16 * 8 = 128
    const int tb  = tid >> 4;          // b-group: 16 * 8 = 128
    const int h0  = blockIdx.x * TN;
    const int b0  = blockIdx.y * TM;
    const int z   = blockIdx.z;
    const int kv_base = z * kchunk;

    float acc[8][8];
    #pragma unroll
    for (int i = 0; i < 8; ++i)
        #pragma unroll
        for (int j = 0; j < 8; ++j) acc[i][j] = 0.0f;

    float4 xv[4], wv[4];

    auto load_regs = [&](int t) {
        int kv = kv_base + t * TK;
        const float* X; const float* W; int k0;
        if (kv < 1024) { X = ha; W = Wha; k0 = kv; }
        else           { X = hf; W = Whf; k0 = kv - 1024; }
        #pragma unroll
        for (int r = 0; r < 4; ++r) {
            int idx = tid + r * 256;
            int row = idx >> 3, kq = idx & 7;
            xv[r] = *reinterpret_cast<const float4*>(X + (size_t)(b0 + row) * Hdim + k0 + kq * 4);
            wv[r] = *reinterpret_cast<const float4*>(W + (size_t)(h0 + row) * Hdim + k0 + kq * 4);
        }
    };

    const int ntiles = kchunk / TK;
    load_regs(0);

    for (int t = 0; t < ntiles; ++t) {
        #pragma unroll
        for (int r = 0; r < 4; ++r) {
            int idx = tid + r * 256;
            int row = idx >> 3, kq = idx & 7;
            As[kq * 4 + 0][row] = xv[r].x;
            As[kq * 4 + 1][row] = xv[r].y;
            As[kq * 4 + 2][row] = xv[r].z;
            As[kq * 4 + 3][row] = xv[r].w;
            Ws[kq * 4 + 0][row] = wv[r].x;
            Ws[kq * 4 + 1][row] = wv[r].y;
            Ws[kq * 4 + 2][row] = wv[r].z;
            Ws[kq * 4 + 3][row] = wv[r].w;
        }
        __syncthreads();

        if (t + 1 < ntiles) load_regs(t + 1);

        #pragma unroll
        for (int k = 0; k < TK; ++k) {
            float4 a0 = *reinterpret_cast<const float4*>(&As[k][tb * 8]);
            float4 a1 = *reinterpret_cast<const float4*>(&As[k][tb * 8 + 4]);
            float4 w0 = *reinterpret_cast<const float4*>(&Ws[k][th * 8]);
            float4 w1 = *reinterpret_cast<const float4*>(&Ws[k][th * 8 + 4]);
            float a[8] = {a0.x, a0.y, a0.z, a0.w, a1.x, a1.y, a1.z, a1.w};
            float w[8] = {w0.x, w0.y, w0.z, w0.w, w1.x, w1.y, w1.z, w1.w};
            #pragma unroll
            for (int i = 0; i < 8; ++i)
                #pragma unroll
                for (int j = 0; j < 8; ++j)
                    acc[i][j] += a[i] * w[j];
        }
        __syncthreads();
    }

    #pragma unroll
    for (int i = 0; i < 8; ++i) {
        int b = b0 + tb * 8 + i;
        __half* dst = qpart + (size_t)z * BH + (size_t)b * Hdim + h0 + th * 8;
        __half2* dst2 = reinterpret_cast<__half2*>(dst);
        dst2[0] = __floats2half2_rn(acc[i][0], acc[i][1]);
        dst2[1] = __floats2half2_rn(acc[i][2], acc[i][3]);
        dst2[2] = __floats2half2_rn(acc[i][4], acc[i][5]);
        dst2[3] = __floats2half2_rn(acc[i][6], acc[i][7]);
    }
}

// ---------------- Fused: reduce-q + scores + softmax + att_res ------------------
// one block per b; 1024 threads = 16 waves. P0 z-split prologue -> 4 LDS slices
// (no combine step; P1 register-load sums slices), P1 scores (q/wa in regs, row
// prefetch, nontemporal), P2 redundant per-wave softmax, P3 att accumulate.
__global__ __launch_bounds__(1024) void fused_kernel(
    const __half* __restrict__ qpart, const float* __restrict__ b_ha,
    const float* __restrict__ b_hf,  const float* __restrict__ p_att,
    const float* __restrict__ w_alpha, const float* __restrict__ b_alpha,
    const float* __restrict__ att_feats, float* __restrict__ out, int ks)
{
    __shared__ __align__(16) float qt[4 * Hdim];   // 4 partial q slices (bias in 0)
    __shared__ __align__(16) float wa_s[Hdim];     // w_alpha
    __shared__ __align__(16) float sc[Sdim];       // raw scores
    __shared__ __align__(16) float part[Fdim];     // half-1 partial for combine
    __shared__ float wred[4];                      // sum(wa) parts

    const int b    = blockIdx.x;
    const int tid  = threadIdx.x;
    const int wave = tid >> 6, lane = tid & 63;

    // ---- P0: z-split qpart reduce (4 groups -> 4 LDS slices) & wa staging ----
    {
        const int zg = tid >> 8;        // 0..3
        const int h4 = tid & 255;       // float4 index into H
        size_t off = (size_t)b * Hdim + h4 * 4;
        float4 s = {0.f, 0.f, 0.f, 0.f};
        for (int z = zg; z < ks; z += 4) {
            const __half2* p2 = reinterpret_cast<const __half2*>(qpart + (size_t)z * BH + off);
            float2 f0 = __half22float2(p2[0]);
            float2 f1 = __half22float2(p2[1]);
            s.x += f0.x; s.y += f0.y; s.z += f1.x; s.w += f1.y;
        }
        if (zg == 0) {
            float4 ba = *reinterpret_cast<const float4*>(b_ha + h4 * 4);
            float4 bb = *reinterpret_cast<const float4*>(b_hf + h4 * 4);
            s.x += ba.x + bb.x; s.y += ba.y + bb.y;
            s.z += ba.z + bb.z; s.w += ba.w + bb.w;
        }
        *reinterpret_cast<float4*>(qt + zg * Hdim + h4 * 4) = s;
        if (zg == 1) {
            float4 w = *reinterpret_cast<const float4*>(w_alpha + h4 * 4);
            *reinterpret_cast<float4*>(wa_s + h4 * 4) = w;
            float ls = w.x + w.y + w.z + w.w;
            #pragma unroll
            for (int m = 32; m >= 1; m >>= 1) ls += __shfl_xor(ls, m, 64);
            if (lane == 0) wred[wave - 4] = ls;
        }
    }
    __syncthreads();

    const float base_sc = wred[0] + wred[1] + wred[2] + wred[3] + b_alpha[0];

    // ---- P1: scores; q/wa in registers (sum 4 slices, scale by C2L) ----
    float4 qr[4], wr[4];
    #pragma unroll
    for (int i = 0; i < 4; ++i) {
        const int idx = (i * 64 + lane) * 4;
        float4 s0 = *reinterpret_cast<const float4*>(qt + idx);
        float4 s1 = *reinterpret_cast<const float4*>(qt + Hdim + idx);
        float4 s2 = *reinterpret_cast<const float4*>(qt + 2 * Hdim + idx);
        float4 s3 = *reinterpret_cast<const float4*>(qt + 3 * Hdim + idx);
        qr[i].x = (s0.x + s1.x + s2.x + s3.x) * C2L;
        qr[i].y = (s0.y + s1.y + s2.y + s3.y) * C2L;
        qr[i].z = (s0.z + s1.z + s2.z + s3.z) * C2L;
        qr[i].w = (s0.w + s1.w + s2.w + s3.w) * C2L;
        wr[i] = *reinterpret_cast<const float4*>(wa_s + idx);
    }

    const float* pbase = p_att + (size_t)b * Sdim * Hdim;
    {
        int s = wave;
        float4 pv[4];
        #pragma unroll
        for (int i = 0; i < 4; ++i)
            pv[i] = ldnt4(pbase + (size_t)s * Hdim + (i * 64 + lane) * 4);
        while (s < Sdim) {
            const int sn = s + 16;
            float4 pn[4];
            if (sn < Sdim) {
                #pragma unroll
                for (int i = 0; i < 4; ++i)
                    pn[i] = ldnt4(pbase + (size_t)sn * Hdim + (i * 64 + lane) * 4);
            }
            float psum = 0.0f;
            #pragma unroll
            for (int i = 0; i < 4; ++i) {
                psum += wr[i].x * __builtin_amdgcn_rcpf(__builtin_amdgcn_exp2f(fmaf(pv[i].x, C2L, qr[i].x)) + 1.0f);
                psum += wr[i].y * __builtin_amdgcn_rcpf(__builtin_amdgcn_exp2f(fmaf(pv[i].y, C2L, qr[i].y)) + 1.0f);
                psum += wr[i].z * __builtin_amdgcn_rcpf(__builtin_amdgcn_exp2f(fmaf(pv[i].z, C2L, qr[i].z)) + 1.0f);
                psum += wr[i].w * __builtin_amdgcn_rcpf(__builtin_amdgcn_exp2f(fmaf(pv[i].w, C2L, qr[i].w)) + 1.0f);
            }
            #pragma unroll
            for (int m = 32; m >= 1; m >>= 1) psum += __shfl_xor(psum, m, 64);
            if (lane == 0) sc[s] = base_sc - 2.0f * psum;
            #pragma unroll
            for (int i = 0; i < 4; ++i) pv[i] = pn[i];
            s = sn;
        }
    }
    __syncthreads();

    // ---- P2: redundant per-wave softmax stats (no LDS writes, no barrier) ----
    float m_max, ssum;
    {
        float v0 = sc[lane];
        float v1 = sc[lane + 64];
        float v2 = sc[lane + 128];
        float v3 = (lane < Sdim - 192) ? sc[lane + 192] : -1e30f;
        float m = fmaxf(fmaxf(v0, v1), fmaxf(v2, v3));
        #pragma unroll
        for (int mk = 32; mk >= 1; mk >>= 1) m = fmaxf(m, __shfl_xor(m, mk, 64));
        float e0 = __builtin_amdgcn_exp2f((v0 - m) * L2E);
        float e1 = __builtin_amdgcn_exp2f((v1 - m) * L2E);
        float e2 = __builtin_amdgcn_exp2f((v2 - m) * L2E);
        float e3 = (lane < Sdim - 192) ? __builtin_amdgcn_exp2f((v3 - m) * L2E) : 0.0f;
        float ss = e0 + e1 + e2 + e3;
        #pragma unroll
        for (int mk = 32; mk >= 1; mk >>= 1) ss += __shfl_xor(ss, mk, 64);
        m_max = m; ssum = ss;
    }

    // ---- P3: att_res accumulate; e = exp2((sc-m)*L2E) on the fly ----
    const int half = tid >> 9;
    const int fi   = (tid & 511) * 4;
    const float* abase = att_feats + (size_t)b * Sdim * Fdim + fi;
    float4 a4 = {0.f, 0.f, 0.f, 0.f};
    const int s0 = half ? 96 : 0;
    const int s1 = half ? 196 : 96;
    int s4 = s0;
    for (; s4 + 8 <= s1; s4 += 8) {
        float4 sa = *reinterpret_cast<const float4*>(sc + s4);
        float4 sb = *reinterpret_cast<const float4*>(sc + s4 + 4);
        float4 v0 = ldnt4(abase + (size_t)(s4 + 0) * Fdim);
        float4 v1 = ldnt4(abase + (size_t)(s4 + 1) * Fdim);
        float4 v2 = ldnt4(abase + (size_t)(s4 + 2) * Fdim);
        float4 v3 = ldnt4(abase + (size_t)(s4 + 3) * Fdim);
        float4 v4 = ldnt4(abase + (size_t)(s4 + 4) * Fdim);
        float4 v5 = ldnt4(abase + (size_t)(s4 + 5) * Fdim);
        float4 v6 = ldnt4(abase + (size_t)(s4 + 6) * Fdim);
        float4 v7 = ldnt4(abase + (size_t)(s4 + 7) * Fdim);
        float e0 = __builtin_amdgcn_exp2f((sa.x - m_max) * L2E);
        float e1 = __builtin_amdgcn_exp2f((sa.y - m_max) * L2E);
        float e2 = __builtin_amdgcn_exp2f((sa.z - m_max) * L2E);
        float e3 = __builtin_amdgcn_exp2f((sa.w - m_max) * L2E);
        float e4 = __builtin_amdgcn_exp2f((sb.x - m_max) * L2E);
        float e5 = __builtin_amdgcn_exp2f((sb.y - m_max) * L2E);
        float e6 = __builtin_amdgcn_exp2f((sb.z - m_max) * L2E);
        float e7 = __builtin_amdgcn_exp2f((sb.w - m_max) * L2E);
        a4.x += e0 * v0.x; a4.y += e0 * v0.y; a4.z += e0 * v0.z; a4.w += e0 * v0.w;
        a4.x += e1 * v1.x; a4.y += e1 * v1.y; a4.z += e1 * v1.z; a4.w += e1 * v1.w;
        a4.x += e2 * v2.x; a4.y += e2 * v2.y; a4.z += e2 * v2.z; a4.w += e2 * v2.w;
        a4.x += e3 * v3.x; a4.y += e3 * v3.y; a4.z += e3 * v3.z; a4.w += e3 * v3.w;
        a4.x += e4 * v4.x; a4.y += e4 * v4.y; a4.z += e4 * v4.z; a4.w += e4 * v4.w;
        a4.x += e5 * v5.x; a4.y += e5 * v5.y; a4.z += e5 * v5.z; a4.w += e5 * v5.w;
        a4.x += e6 * v6.x; a4.y += e6 * v6.y; a4.z += e6 * v6.z; a4.w += e6 * v6.w;
        a4.x += e7 * v7.x; a4.y += e7 * v7.y; a4.z += e7 * v7.z; a4.w += e7 * v7.w;
    }
    if (s4 < s1) {   // tail of 4 (only half 1: s = 192..195)
        float4 sa = *reinterpret_cast<const float4*>(sc + s4);
        float4 v0 = ldnt4(abase + (size_t)(s4 + 0) * Fdim);
        float4 v1 = ldnt4(abase + (size_t)(s4 + 1) * Fdim);
        float4 v2 = ldnt4(abase + (size_t)(s4 + 2) * Fdim);
        float4 v3 = ldnt4(abase + (size_t)(s4 + 3) * Fdim);
        float e0 = __builtin_amdgcn_exp2f((sa.x - m_max) * L2E);
        float e1 = __builtin_amdgcn_exp2f((sa.y - m_max) * L2E);
        float e2 = __builtin_amdgcn_exp2f((sa.z - m_max) * L2E);
        float e3 = __builtin_amdgcn_exp2f((sa.w - m_max) * L2E);
        a4.x += e0 * v0.x; a4.y += e0 * v0.y; a4.z += e0 * v0.z; a4.w += e0 * v0.w;
        a4.x += e1 * v1.x; a4.y += e1 * v1.y; a4.z += e1 * v1.z; a4.w += e1 * v1.w;
        a4.x += e2 * v2.x; a4.y += e2 * v2.y; a4.z += e2 * v2.z; a4.w += e2 * v2.w;
        a4.x += e3 * v3.x; a4.y += e3 * v3.y; a4.z += e3 * v3.z; a4.w += e3 * v3.w;
    }
    if (half) {
        *reinterpret_cast<float4*>(part + fi) = a4;
    }
    __syncthreads();
    if (!half) {
        const float winv = __builtin_amdgcn_rcpf(ssum);
        float4 p4 = *reinterpret_cast<const float4*>(part + fi);
        a4.x = (a4.x + p4.x) * winv; a4.y = (a4.y + p4.y) * winv;
        a4.z = (a4.z + p4.z) * winv; a4.w = (a4.w + p4.w) * winv;
        *reinterpret_cast<float4*>(out + (size_t)b * Fdim + fi) = a4;
    }
}

// ---------------- launch --------------------------------------------------------
extern "C" void kernel_launch(void* const* d_in, const int* in_sizes, int n_in,
                              void* d_out, int out_size, void* d_ws, size_t ws_size,
                              hipStream_t stream) {
    const float* ha       = (const float*)d_in[0];
    const float* hf       = (const float*)d_in[1];
    const float* att_f    = (const float*)d_in[2];
    const float* p_att    = (const float*)d_in[3];
    const float* W_ha     = (const float*)d_in[4];
    const float* b_ha     = (const float*)d_in[5];
    const float* W_hf     = (const float*)d_in[6];
    const float* b_hf     = (const float*)d_in[7];
    const float* w_alpha  = (const float*)d_in[8];
    const float* b_alpha  = (const float*)d_in[9];
    float* out = (float*)d_out;
    __half* qpart = (__half*)d_ws;

    int KS = 32;
    while (KS > 1 && ((size_t)KS * BH) * sizeof(__half) > ws_size) KS >>= 1;

    dim3 gA(Hdim / TN, Bdim / TM, KS);
    gemm_q_part<<<gA, 256, 0, stream>>>(ha, hf, W_ha, W_hf, qpart, 2048 / KS);

    fused_kernel<<<dim3(Bdim), 1024, 0, stream>>>(
        qpart, b_ha, b_hf, p_att, w_alpha, b_alpha, att_f, out, KS);
}

// Round 8
// 108.702 us; speedup vs baseline: 1.1089x; 1.1089x over previous
//
#include <hip/hip_runtime.h>
#include <hip/hip_bf16.h>
#include <hip/hip_fp16.h>

#define Bdim 256
#define Sdim 196
#define Hdim 1024
#define Fdim 2048
#define BH (Bdim*Hdim)      // 262144
#define L2E 1.44269504f
#define C2L 2.88539008f     // 2*log2(e)
#define KSPLIT 16

typedef float nfloat4 __attribute__((ext_vector_type(4)));
typedef _Float16 half8 __attribute__((ext_vector_type(8)));
typedef float f32x4 __attribute__((ext_vector_type(4)));

__device__ __forceinline__ float4 ldnt4(const float* p) {
    nfloat4 v = __builtin_nontemporal_load(reinterpret_cast<const nfloat4*>(p));
    return make_float4(v.x, v.y, v.z, v.w);
}

// ---------------- Kernel A: qpart(fp16) via f16 MFMA ----------------------------
// grid (8 h-tiles, 2 b-tiles, 16 z); 256 threads = 4 waves (2x2, 64x64 each).
// tile 128x128, kchunk=128 staged as two 64-k halves; LDS f16 XOR-swizzled.
__global__ __launch_bounds__(256) void gemm_q_mfma(
    const float* __restrict__ ha, const float* __restrict__ hf,
    const float* __restrict__ Wha, const float* __restrict__ Whf,
    __half* __restrict__ qpart)
{
    __shared__ __align__(16) _Float16 As[128 * 64];   // [row][64k] swizzled
    __shared__ __align__(16) _Float16 Bs[128 * 64];
    __shared__ __align__(16) float bounce[128 * 132]; // +4 pad per row

    const int tid  = threadIdx.x;
    const int lane = tid & 63;
    const int wave = tid >> 6;              // 0..3
    const int wr   = wave >> 1;             // 0..1 (b-half of tile)
    const int wc   = wave & 1;              // 0..1 (h-half of tile)
    const int h0   = blockIdx.x * 128;
    const int b0   = blockIdx.y * 128;
    const int z    = blockIdx.z;            // 0..15
    const int kv   = z * 128;               // virtual k base (0..2047)

    const float* X; const float* W; int k0;
    if (kv < 1024) { X = ha; W = Wha; k0 = kv; }
    else           { X = hf; W = Whf; k0 = kv - 1024; }

    f32x4 acc[4][4];
    #pragma unroll
    for (int m = 0; m < 4; ++m)
        #pragma unroll
        for (int n = 0; n < 4; ++n) acc[m][n] = (f32x4){0.f, 0.f, 0.f, 0.f};

    float4 xa[8], xb[8];

    // stage unit: u = tid + i*256; row = u>>4 (0..127), c4 = u&15 (float4 col)
    auto issue_loads = [&](int khalf) {
        const int kh = k0 + khalf * 64;
        #pragma unroll
        for (int i = 0; i < 8; ++i) {
            int u = tid + i * 256;
            int row = u >> 4, c4 = u & 15;
            xa[i] = *reinterpret_cast<const float4*>(X + (size_t)(b0 + row) * Hdim + kh + c4 * 4);
            xb[i] = *reinterpret_cast<const float4*>(W + (size_t)(h0 + row) * Hdim + kh + c4 * 4);
        }
    };

    auto st4h = [&](_Float16* base, int byte, float4 v) {
        _Float16 t[4] = {(_Float16)v.x, (_Float16)v.y, (_Float16)v.z, (_Float16)v.w};
        *reinterpret_cast<uint2*>(reinterpret_cast<char*>(base) + byte) =
            *reinterpret_cast<uint2*>(t);
    };

    auto write_lds = [&]() {
        #pragma unroll
        for (int i = 0; i < 8; ++i) {
            int u = tid + i * 256;
            int row = u >> 4, c4 = u & 15;
            int byte = row * 128 + ((c4 * 8) ^ ((row & 7) << 4));   // 8B per unit
            st4h(As, byte, xa[i]);
            st4h(Bs, byte, xb[i]);
        }
    };

    auto mfma_half = [&]() {
        #pragma unroll
        for (int kk = 0; kk < 2; ++kk) {
            half8 af[4], bf[4];
            const int k8 = kk * 4 + (lane >> 4);        // 16B unit in 64-k row
            #pragma unroll
            for (int m = 0; m < 4; ++m) {
                int row = wr * 64 + m * 16 + (lane & 15);
                int byte = row * 128 + ((k8 * 16) ^ ((row & 7) << 4));
                af[m] = *reinterpret_cast<half8*>(reinterpret_cast<char*>(As) + byte);
            }
            #pragma unroll
            for (int n = 0; n < 4; ++n) {
                int row = wc * 64 + n * 16 + (lane & 15);
                int byte = row * 128 + ((k8 * 16) ^ ((row & 7) << 4));
                bf[n] = *reinterpret_cast<half8*>(reinterpret_cast<char*>(Bs) + byte);
            }
            #pragma unroll
            for (int m = 0; m < 4; ++m)
                #pragma unroll
                for (int n = 0; n < 4; ++n)
                    acc[m][n] = __builtin_amdgcn_mfma_f32_16x16x32_f16(
                        af[m], bf[n], acc[m][n], 0, 0, 0);
        }
    };

    issue_loads(0);
    write_lds();                 // compiler waits on xa/xb
    __syncthreads();
    issue_loads(1);              // prefetch half 1 under half-0 MFMA
    mfma_half();
    __syncthreads();             // all frag reads of half 0 done
    write_lds();
    __syncthreads();
    mfma_half();

    // ---- epilogue: acc -> bounce (f32, padded) -> coalesced fp16 qpart ----
    #pragma unroll
    for (int m = 0; m < 4; ++m)
        #pragma unroll
        for (int n = 0; n < 4; ++n)
            #pragma unroll
            for (int j = 0; j < 4; ++j) {
                int r = wr * 64 + m * 16 + (lane >> 4) * 4 + j;
                int c = wc * 64 + n * 16 + (lane & 15);
                bounce[r * 132 + c] = acc[m][n][j];
            }
    __syncthreads();

    __half* qbase = qpart + (size_t)z * BH;
    #pragma unroll
    for (int i = 0; i < 8; ++i) {
        int u = tid + i * 256;
        int row = u >> 4, ch = u & 15;       // 16 chunks of 8 halfs per row
        const float* src = bounce + row * 132 + ch * 8;
        __half2 p[4];
        #pragma unroll
        for (int j = 0; j < 4; ++j) p[j] = __floats2half2_rn(src[2 * j], src[2 * j + 1]);
        *reinterpret_cast<float4*>(qbase + (size_t)(b0 + row) * Hdim + h0 + ch * 8) =
            *reinterpret_cast<float4*>(p);
    }
}

// ---------------- Fused: reduce-q + scores + softmax + att_res ------------------
// one block per b; 1024 threads = 16 waves. P0 z-split prologue -> 4 LDS slices
// (no combine step; P1 register-load sums slices), P1 scores (q/wa in regs, row
// prefetch, nontemporal), P2 redundant per-wave softmax, P3 att accumulate.
__global__ __launch_bounds__(1024) void fused_kernel(
    const __half* __restrict__ qpart, const float* __restrict__ b_ha,
    const float* __restrict__ b_hf,  const float* __restrict__ p_att,
    const float* __restrict__ w_alpha, const float* __restrict__ b_alpha,
    const float* __restrict__ att_feats, float* __restrict__ out, int ks)
{
    __shared__ __align__(16) float qt[4 * Hdim];   // 4 partial q slices (bias in 0)
    __shared__ __align__(16) float wa_s[Hdim];     // w_alpha
    __shared__ __align__(16) float sc[Sdim];       // raw scores
    __shared__ __align__(16) float part[Fdim];     // half-1 partial for combine
    __shared__ float wred[4];                      // sum(wa) parts

    const int b    = blockIdx.x;
    const int tid  = threadIdx.x;
    const int wave = tid >> 6, lane = tid & 63;

    // ---- P0: z-split qpart reduce (4 groups -> 4 LDS slices) & wa staging ----
    {
        const int zg = tid >> 8;        // 0..3
        const int h4 = tid & 255;       // float4 index into H
        size_t off = (size_t)b * Hdim + h4 * 4;
        float4 s = {0.f, 0.f, 0.f, 0.f};
        for (int z = zg; z < ks; z += 4) {
            const __half2* p2 = reinterpret_cast<const __half2*>(qpart + (size_t)z * BH + off);
            float2 f0 = __half22float2(p2[0]);
            float2 f1 = __half22float2(p2[1]);
            s.x += f0.x; s.y += f0.y; s.z += f1.x; s.w += f1.y;
        }
        if (zg == 0) {
            float4 ba = *reinterpret_cast<const float4*>(b_ha + h4 * 4);
            float4 bb = *reinterpret_cast<const float4*>(b_hf + h4 * 4);
            s.x += ba.x + bb.x; s.y += ba.y + bb.y;
            s.z += ba.z + bb.z; s.w += ba.w + bb.w;
        }
        *reinterpret_cast<float4*>(qt + zg * Hdim + h4 * 4) = s;
        if (zg == 1) {
            float4 w = *reinterpret_cast<const float4*>(w_alpha + h4 * 4);
            *reinterpret_cast<float4*>(wa_s + h4 * 4) = w;
            float ls = w.x + w.y + w.z + w.w;
            #pragma unroll
            for (int m = 32; m >= 1; m >>= 1) ls += __shfl_xor(ls, m, 64);
            if (lane == 0) wred[wave - 4] = ls;
        }
    }
    __syncthreads();

    const float base_sc = wred[0] + wred[1] + wred[2] + wred[3] + b_alpha[0];

    // ---- P1: scores; q/wa in registers (sum 4 slices, scale by C2L) ----
    float4 qr[4], wr[4];
    #pragma unroll
    for (int i = 0; i < 4; ++i) {
        const int idx = (i * 64 + lane) * 4;
        float4 s0 = *reinterpret_cast<const float4*>(qt + idx);
        float4 s1 = *reinterpret_cast<const float4*>(qt + Hdim + idx);
        float4 s2 = *reinterpret_cast<const float4*>(qt + 2 * Hdim + idx);
        float4 s3 = *reinterpret_cast<const float4*>(qt + 3 * Hdim + idx);
        qr[i].x = (s0.x + s1.x + s2.x + s3.x) * C2L;
        qr[i].y = (s0.y + s1.y + s2.y + s3.y) * C2L;
        qr[i].z = (s0.z + s1.z + s2.z + s3.z) * C2L;
        qr[i].w = (s0.w + s1.w + s2.w + s3.w) * C2L;
        wr[i] = *reinterpret_cast<const float4*>(wa_s + idx);
    }

    const float* pbase = p_att + (size_t)b * Sdim * Hdim;
    {
        int s = wave;
        float4 pv[4];
        #pragma unroll
        for (int i = 0; i < 4; ++i)
            pv[i] = ldnt4(pbase + (size_t)s * Hdim + (i * 64 + lane) * 4);
        while (s < Sdim) {
            const int sn = s + 16;
            float4 pn[4];
            if (sn < Sdim) {
                #pragma unroll
                for (int i = 0; i < 4; ++i)
                    pn[i] = ldnt4(pbase + (size_t)sn * Hdim + (i * 64 + lane) * 4);
            }
            float psum = 0.0f;
            #pragma unroll
            for (int i = 0; i < 4; ++i) {
                psum += wr[i].x * __builtin_amdgcn_rcpf(__builtin_amdgcn_exp2f(fmaf(pv[i].x, C2L, qr[i].x)) + 1.0f);
                psum += wr[i].y * __builtin_amdgcn_rcpf(__builtin_amdgcn_exp2f(fmaf(pv[i].y, C2L, qr[i].y)) + 1.0f);
                psum += wr[i].z * __builtin_amdgcn_rcpf(__builtin_amdgcn_exp2f(fmaf(pv[i].z, C2L, qr[i].z)) + 1.0f);
                psum += wr[i].w * __builtin_amdgcn_rcpf(__builtin_amdgcn_exp2f(fmaf(pv[i].w, C2L, qr[i].w)) + 1.0f);
            }
            #pragma unroll
            for (int m = 32; m >= 1; m >>= 1) psum += __shfl_xor(psum, m, 64);
            if (lane == 0) sc[s] = base_sc - 2.0f * psum;
            #pragma unroll
            for (int i = 0; i < 4; ++i) pv[i] = pn[i];
            s = sn;
        }
    }
    __syncthreads();

    // ---- P2: redundant per-wave softmax stats (no LDS writes, no barrier) ----
    float m_max, ssum;
    {
        float v0 = sc[lane];
        float v1 = sc[lane + 64];
        float v2 = sc[lane + 128];
        float v3 = (lane < Sdim - 192) ? sc[lane + 192] : -1e30f;
        float m = fmaxf(fmaxf(v0, v1), fmaxf(v2, v3));
        #pragma unroll
        for (int mk = 32; mk >= 1; mk >>= 1) m = fmaxf(m, __shfl_xor(m, mk, 64));
        float e0 = __builtin_amdgcn_exp2f((v0 - m) * L2E);
        float e1 = __builtin_amdgcn_exp2f((v1 - m) * L2E);
        float e2 = __builtin_amdgcn_exp2f((v2 - m) * L2E);
        float e3 = (lane < Sdim - 192) ? __builtin_amdgcn_exp2f((v3 - m) * L2E) : 0.0f;
        float ss = e0 + e1 + e2 + e3;
        #pragma unroll
        for (int mk = 32; mk >= 1; mk >>= 1) ss += __shfl_xor(ss, mk, 64);
        m_max = m; ssum = ss;
    }

    // ---- P3: att_res accumulate; e = exp2((sc-m)*L2E) on the fly ----
    const int half = tid >> 9;
    const int fi   = (tid & 511) * 4;
    const float* abase = att_feats + (size_t)b * Sdim * Fdim + fi;
    float4 a4 = {0.f, 0.f, 0.f, 0.f};
    const int s0 = half ? 96 : 0;
    const int s1 = half ? 196 : 96;
    int s4 = s0;
    for (; s4 + 8 <= s1; s4 += 8) {
        float4 sa = *reinterpret_cast<const float4*>(sc + s4);
        float4 sb = *reinterpret_cast<const float4*>(sc + s4 + 4);
        float4 v0 = ldnt4(abase + (size_t)(s4 + 0) * Fdim);
        float4 v1 = ldnt4(abase + (size_t)(s4 + 1) * Fdim);
        float4 v2 = ldnt4(abase + (size_t)(s4 + 2) * Fdim);
        float4 v3 = ldnt4(abase + (size_t)(s4 + 3) * Fdim);
        float4 v4 = ldnt4(abase + (size_t)(s4 + 4) * Fdim);
        float4 v5 = ldnt4(abase + (size_t)(s4 + 5) * Fdim);
        float4 v6 = ldnt4(abase + (size_t)(s4 + 6) * Fdim);
        float4 v7 = ldnt4(abase + (size_t)(s4 + 7) * Fdim);
        float e0 = __builtin_amdgcn_exp2f((sa.x - m_max) * L2E);
        float e1 = __builtin_amdgcn_exp2f((sa.y - m_max) * L2E);
        float e2 = __builtin_amdgcn_exp2f((sa.z - m_max) * L2E);
        float e3 = __builtin_amdgcn_exp2f((sa.w - m_max) * L2E);
        float e4 = __builtin_amdgcn_exp2f((sb.x - m_max) * L2E);
        float e5 = __builtin_amdgcn_exp2f((sb.y - m_max) * L2E);
        float e6 = __builtin_amdgcn_exp2f((sb.z - m_max) * L2E);
        float e7 = __builtin_amdgcn_exp2f((sb.w - m_max) * L2E);
        a4.x += e0 * v0.x; a4.y += e0 * v0.y; a4.z += e0 * v0.z; a4.w += e0 * v0.w;
        a4.x += e1 * v1.x; a4.y += e1 * v1.y; a4.z += e1 * v1.z; a4.w += e1 * v1.w;
        a4.x += e2 * v2.x; a4.y += e2 * v2.y; a4.z += e2 * v2.z; a4.w += e2 * v2.w;
        a4.x += e3 * v3.x; a4.y += e3 * v3.y; a4.z += e3 * v3.z; a4.w += e3 * v3.w;
        a4.x += e4 * v4.x; a4.y += e4 * v4.y; a4.z += e4 * v4.z; a4.w += e4 * v4.w;
        a4.x += e5 * v5.x; a4.y += e5 * v5.y; a4.z += e5 * v5.z; a4.w += e5 * v5.w;
        a4.x += e6 * v6.x; a4.y += e6 * v6.y; a4.z += e6 * v6.z; a4.w += e6 * v6.w;
        a4.x += e7 * v7.x; a4.y += e7 * v7.y; a4.z += e7 * v7.z; a4.w += e7 * v7.w;
    }
    if (s4 < s1) {   // tail of 4 (only half 1: s = 192..195)
        float4 sa = *reinterpret_cast<const float4*>(sc + s4);
        float4 v0 = ldnt4(abase + (size_t)(s4 + 0) * Fdim);
        float4 v1 = ldnt4(abase + (size_t)(s4 + 1) * Fdim);
        float4 v2 = ldnt4(abase + (size_t)(s4 + 2) * Fdim);
        float4 v3 = ldnt4(abase + (size_t)(s4 + 3) * Fdim);
        float e0 = __builtin_amdgcn_exp2f((sa.x - m_max) * L2E);
        float e1 = __builtin_amdgcn_exp2f((sa.y - m_max) * L2E);
        float e2 = __builtin_amdgcn_exp2f((sa.z - m_max) * L2E);
        float e3 = __builtin_amdgcn_exp2f((sa.w - m_max) * L2E);
        a4.x += e0 * v0.x; a4.y += e0 * v0.y; a4.z += e0 * v0.z; a4.w += e0 * v0.w;
        a4.x += e1 * v1.x; a4.y += e1 * v1.y; a4.z += e1 * v1.z; a4.w += e1 * v1.w;
        a4.x += e2 * v2.x; a4.y += e2 * v2.y; a4.z += e2 * v2.z; a4.w += e2 * v2.w;
        a4.x += e3 * v3.x; a4.y += e3 * v3.y; a4.z += e3 * v3.z; a4.w += e3 * v3.w;
    }
    if (half) {
        *reinterpret_cast<float4*>(part + fi) = a4;
    }
    __syncthreads();
    if (!half) {
        const float winv = __builtin_amdgcn_rcpf(ssum);
        float4 p4 = *reinterpret_cast<const float4*>(part + fi);
        a4.x = (a4.x + p4.x) * winv; a4.y = (a4.y + p4.y) * winv;
        a4.z = (a4.z + p4.z) * winv; a4.w = (a4.w + p4.w) * winv;
        *reinterpret_cast<float4*>(out + (size_t)b * Fdim + fi) = a4;
    }
}

// ---------------- launch --------------------------------------------------------
extern "C" void kernel_launch(void* const* d_in, const int* in_sizes, int n_in,
                              void* d_out, int out_size, void* d_ws, size_t ws_size,
                              hipStream_t stream) {
    const float* ha       = (const float*)d_in[0];
    const float* hf       = (const float*)d_in[1];
    const float* att_f    = (const float*)d_in[2];
    const float* p_att    = (const float*)d_in[3];
    const float* W_ha     = (const float*)d_in[4];
    const float* b_ha     = (const float*)d_in[5];
    const float* W_hf     = (const float*)d_in[6];
    const float* b_hf     = (const float*)d_in[7];
    const float* w_alpha  = (const float*)d_in[8];
    const float* b_alpha  = (const float*)d_in[9];
    float* out = (float*)d_out;
    __half* qpart = (__half*)d_ws;

    dim3 gA(Hdim / 128, Bdim / 128, KSPLIT);
    gemm_q_mfma<<<gA, 256, 0, stream>>>(ha, hf, W_ha, W_hf, qpart);

    fused_kernel<<<dim3(Bdim), 1024, 0, stream>>>(
        qpart, b_ha, b_hf, p_att, w_alpha, b_alpha, att_f, out, KSPLIT);
}

// Round 9
// 108.186 us; speedup vs baseline: 1.1142x; 1.0048x over previous
//
#include <hip/hip_runtime.h>
#include <hip/hip_bf16.h>
#include <hip/hip_fp16.h>

#define Bdim 256
#define Sdim 196
#define Hdim 1024
#define Fdim 2048
#define BH (Bdim*Hdim)      // 262144
#define L2E 1.44269504f
#define C2L 2.88539008f     // 2*log2(e)
#define KSPLIT 16

typedef float nfloat4 __attribute__((ext_vector_type(4)));
typedef _Float16 half8 __attribute__((ext_vector_type(8)));
typedef float f32x4 __attribute__((ext_vector_type(4)));

__device__ __forceinline__ float4 ldnt4(const float* p) {
    nfloat4 v = __builtin_nontemporal_load(reinterpret_cast<const nfloat4*>(p));
    return make_float4(v.x, v.y, v.z, v.w);
}

// ---------------- Kernel A: qpart(fp16) via f16 MFMA ----------------------------
// grid (8 h-tiles, 2 b-tiles, 16 z); 256 threads = 4 waves (2x2, 64x64 each).
// tile 128x128, kchunk=128 staged as two 64-k halves; LDS f16 XOR-swizzled.
__global__ __launch_bounds__(256) void gemm_q_mfma(
    const float* __restrict__ ha, const float* __restrict__ hf,
    const float* __restrict__ Wha, const float* __restrict__ Whf,
    __half* __restrict__ qpart)
{
    __shared__ __align__(16) _Float16 As[128 * 64];   // [row][64k] swizzled
    __shared__ __align__(16) _Float16 Bs[128 * 64];
    __shared__ __align__(16) float bounce[128 * 132]; // +4 pad per row

    const int tid  = threadIdx.x;
    const int lane = tid & 63;
    const int wave = tid >> 6;              // 0..3
    const int wr   = wave >> 1;             // 0..1 (b-half of tile)
    const int wc   = wave & 1;              // 0..1 (h-half of tile)
    const int h0   = blockIdx.x * 128;
    const int b0   = blockIdx.y * 128;
    const int z    = blockIdx.z;            // 0..15
    const int kv   = z * 128;               // virtual k base (0..2047)

    const float* X; const float* W; int k0;
    if (kv < 1024) { X = ha; W = Wha; k0 = kv; }
    else           { X = hf; W = Whf; k0 = kv - 1024; }

    f32x4 acc[4][4];
    #pragma unroll
    for (int m = 0; m < 4; ++m)
        #pragma unroll
        for (int n = 0; n < 4; ++n) acc[m][n] = (f32x4){0.f, 0.f, 0.f, 0.f};

    float4 xa[8], xb[8];

    // stage unit: u = tid + i*256; row = u>>4 (0..127), c4 = u&15 (float4 col)
    auto issue_loads = [&](int khalf) {
        const int kh = k0 + khalf * 64;
        #pragma unroll
        for (int i = 0; i < 8; ++i) {
            int u = tid + i * 256;
            int row = u >> 4, c4 = u & 15;
            xa[i] = *reinterpret_cast<const float4*>(X + (size_t)(b0 + row) * Hdim + kh + c4 * 4);
            xb[i] = *reinterpret_cast<const float4*>(W + (size_t)(h0 + row) * Hdim + kh + c4 * 4);
        }
    };

    auto st4h = [&](_Float16* base, int byte, float4 v) {
        _Float16 t[4] = {(_Float16)v.x, (_Float16)v.y, (_Float16)v.z, (_Float16)v.w};
        *reinterpret_cast<uint2*>(reinterpret_cast<char*>(base) + byte) =
            *reinterpret_cast<uint2*>(t);
    };

    auto write_lds = [&]() {
        #pragma unroll
        for (int i = 0; i < 8; ++i) {
            int u = tid + i * 256;
            int row = u >> 4, c4 = u & 15;
            int byte = row * 128 + ((c4 * 8) ^ ((row & 7) << 4));   // 8B per unit
            st4h(As, byte, xa[i]);
            st4h(Bs, byte, xb[i]);
        }
    };

    auto mfma_half = [&]() {
        #pragma unroll
        for (int kk = 0; kk < 2; ++kk) {
            half8 af[4], bf[4];
            const int k8 = kk * 4 + (lane >> 4);        // 16B unit in 64-k row
            #pragma unroll
            for (int m = 0; m < 4; ++m) {
                int row = wr * 64 + m * 16 + (lane & 15);
                int byte = row * 128 + ((k8 * 16) ^ ((row & 7) << 4));
                af[m] = *reinterpret_cast<half8*>(reinterpret_cast<char*>(As) + byte);
            }
            #pragma unroll
            for (int n = 0; n < 4; ++n) {
                int row = wc * 64 + n * 16 + (lane & 15);
                int byte = row * 128 + ((k8 * 16) ^ ((row & 7) << 4));
                bf[n] = *reinterpret_cast<half8*>(reinterpret_cast<char*>(Bs) + byte);
            }
            #pragma unroll
            for (int m = 0; m < 4; ++m)
                #pragma unroll
                for (int n = 0; n < 4; ++n)
                    acc[m][n] = __builtin_amdgcn_mfma_f32_16x16x32_f16(
                        af[m], bf[n], acc[m][n], 0, 0, 0);
        }
    };

    issue_loads(0);
    write_lds();                 // compiler waits on xa/xb
    __syncthreads();
    issue_loads(1);              // prefetch half 1 under half-0 MFMA
    mfma_half();
    __syncthreads();             // all frag reads of half 0 done
    write_lds();
    __syncthreads();
    mfma_half();

    // ---- epilogue: acc -> bounce (f32, padded) -> coalesced fp16 qpart ----
    #pragma unroll
    for (int m = 0; m < 4; ++m)
        #pragma unroll
        for (int n = 0; n < 4; ++n)
            #pragma unroll
            for (int j = 0; j < 4; ++j) {
                int r = wr * 64 + m * 16 + (lane >> 4) * 4 + j;
                int c = wc * 64 + n * 16 + (lane & 15);
                bounce[r * 132 + c] = acc[m][n][j];
            }
    __syncthreads();

    __half* qbase = qpart + (size_t)z * BH;
    #pragma unroll
    for (int i = 0; i < 8; ++i) {
        int u = tid + i * 256;
        int row = u >> 4, ch = u & 15;       // 16 chunks of 8 halfs per row
        const float* src = bounce + row * 132 + ch * 8;
        __half2 p[4];
        #pragma unroll
        for (int j = 0; j < 4; ++j) p[j] = __floats2half2_rn(src[2 * j], src[2 * j + 1]);
        *reinterpret_cast<float4*>(qbase + (size_t)(b0 + row) * Hdim + h0 + ch * 8) =
            *reinterpret_cast<float4*>(p);
    }
}

// ---------------- Fused: reduce-q + scores + softmax + att_res ------------------
// one block per b; 1024 threads = 16 waves. Early p_att prefetch hides P0;
// att_feats prefetch before the P1->P3 barrier hides the phase-boundary bubble.
__global__ __launch_bounds__(1024) void fused_kernel(
    const __half* __restrict__ qpart, const float* __restrict__ b_ha,
    const float* __restrict__ b_hf,  const float* __restrict__ p_att,
    const float* __restrict__ w_alpha, const float* __restrict__ b_alpha,
    const float* __restrict__ att_feats, float* __restrict__ out, int ks)
{
    __shared__ __align__(16) float qt[4 * Hdim];   // 4 partial q slices (bias in 0)
    __shared__ __align__(16) float wa_s[Hdim];     // w_alpha
    __shared__ __align__(16) float sc[Sdim];       // raw scores
    __shared__ __align__(16) float part[Fdim];     // half-1 partial for combine
    __shared__ float wred[4];                      // sum(wa) parts

    const int b    = blockIdx.x;
    const int tid  = threadIdx.x;
    const int wave = tid >> 6, lane = tid & 63;
    const int half = tid >> 9;
    const int fi   = (tid & 511) * 4;

    const float* pbase = p_att     + (size_t)b * Sdim * Hdim;
    const float* abase = att_feats + (size_t)b * Sdim * Fdim + fi;

    // ---- early prefetch: first P1 row for this wave (independent of P0) ----
    float4 pv[4];
    #pragma unroll
    for (int i = 0; i < 4; ++i)
        pv[i] = ldnt4(pbase + (size_t)wave * Hdim + (i * 64 + lane) * 4);

    // ---- P0: z-split qpart reduce (4 groups -> 4 LDS slices) & wa staging ----
    {
        const int zg = tid >> 8;        // 0..3
        const int h4 = tid & 255;       // float4 index into H
        size_t off = (size_t)b * Hdim + h4 * 4;
        float4 s = {0.f, 0.f, 0.f, 0.f};
        for (int z = zg; z < ks; z += 4) {
            const __half2* p2 = reinterpret_cast<const __half2*>(qpart + (size_t)z * BH + off);
            float2 f0 = __half22float2(p2[0]);
            float2 f1 = __half22float2(p2[1]);
            s.x += f0.x; s.y += f0.y; s.z += f1.x; s.w += f1.y;
        }
        if (zg == 0) {
            float4 ba = *reinterpret_cast<const float4*>(b_ha + h4 * 4);
            float4 bb = *reinterpret_cast<const float4*>(b_hf + h4 * 4);
            s.x += ba.x + bb.x; s.y += ba.y + bb.y;
            s.z += ba.z + bb.z; s.w += ba.w + bb.w;
        }
        *reinterpret_cast<float4*>(qt + zg * Hdim + h4 * 4) = s;
        if (zg == 1) {
            float4 w = *reinterpret_cast<const float4*>(w_alpha + h4 * 4);
            *reinterpret_cast<float4*>(wa_s + h4 * 4) = w;
            float ls = w.x + w.y + w.z + w.w;
            #pragma unroll
            for (int m = 32; m >= 1; m >>= 1) ls += __shfl_xor(ls, m, 64);
            if (lane == 0) wred[wave - 4] = ls;
        }
    }
    __syncthreads();

    const float base_sc = wred[0] + wred[1] + wred[2] + wred[3] + b_alpha[0];

    // ---- P1: scores; q/wa in registers (sum 4 slices, scale by C2L) ----
    float4 qr[4], wr[4];
    #pragma unroll
    for (int i = 0; i < 4; ++i) {
        const int idx = (i * 64 + lane) * 4;
        float4 s0v = *reinterpret_cast<const float4*>(qt + idx);
        float4 s1v = *reinterpret_cast<const float4*>(qt + Hdim + idx);
        float4 s2v = *reinterpret_cast<const float4*>(qt + 2 * Hdim + idx);
        float4 s3v = *reinterpret_cast<const float4*>(qt + 3 * Hdim + idx);
        qr[i].x = (s0v.x + s1v.x + s2v.x + s3v.x) * C2L;
        qr[i].y = (s0v.y + s1v.y + s2v.y + s3v.y) * C2L;
        qr[i].z = (s0v.z + s1v.z + s2v.z + s3v.z) * C2L;
        qr[i].w = (s0v.w + s1v.w + s2v.w + s3v.w) * C2L;
        wr[i] = *reinterpret_cast<const float4*>(wa_s + idx);
    }

    {
        int s = wave;
        while (s < Sdim) {
            const int sn = s + 16;
            float4 pn[4];
            if (sn < Sdim) {
                #pragma unroll
                for (int i = 0; i < 4; ++i)
                    pn[i] = ldnt4(pbase + (size_t)sn * Hdim + (i * 64 + lane) * 4);
            }
            float psum = 0.0f;
            #pragma unroll
            for (int i = 0; i < 4; ++i) {
                psum += wr[i].x * __builtin_amdgcn_rcpf(__builtin_amdgcn_exp2f(fmaf(pv[i].x, C2L, qr[i].x)) + 1.0f);
                psum += wr[i].y * __builtin_amdgcn_rcpf(__builtin_amdgcn_exp2f(fmaf(pv[i].y, C2L, qr[i].y)) + 1.0f);
                psum += wr[i].z * __builtin_amdgcn_rcpf(__builtin_amdgcn_exp2f(fmaf(pv[i].z, C2L, qr[i].z)) + 1.0f);
                psum += wr[i].w * __builtin_amdgcn_rcpf(__builtin_amdgcn_exp2f(fmaf(pv[i].w, C2L, qr[i].w)) + 1.0f);
            }
            #pragma unroll
            for (int m = 32; m >= 1; m >>= 1) psum += __shfl_xor(psum, m, 64);
            if (lane == 0) sc[s] = base_sc - 2.0f * psum;
            #pragma unroll
            for (int i = 0; i < 4; ++i) pv[i] = pn[i];
            s = sn;
        }
    }

    // ---- prefetch first 8 att rows for P3 (independent of scores) ----
    const int s0 = half ? 96 : 0;
    const int s1 = half ? 196 : 96;
    float4 av0 = ldnt4(abase + (size_t)(s0 + 0) * Fdim);
    float4 av1 = ldnt4(abase + (size_t)(s0 + 1) * Fdim);
    float4 av2 = ldnt4(abase + (size_t)(s0 + 2) * Fdim);
    float4 av3 = ldnt4(abase + (size_t)(s0 + 3) * Fdim);
    float4 av4 = ldnt4(abase + (size_t)(s0 + 4) * Fdim);
    float4 av5 = ldnt4(abase + (size_t)(s0 + 5) * Fdim);
    float4 av6 = ldnt4(abase + (size_t)(s0 + 6) * Fdim);
    float4 av7 = ldnt4(abase + (size_t)(s0 + 7) * Fdim);
    __syncthreads();

    // ---- P2: redundant per-wave softmax stats (no LDS writes, no barrier) ----
    float m_max, ssum;
    {
        float v0 = sc[lane];
        float v1 = sc[lane + 64];
        float v2 = sc[lane + 128];
        float v3 = (lane < Sdim - 192) ? sc[lane + 192] : -1e30f;
        float m = fmaxf(fmaxf(v0, v1), fmaxf(v2, v3));
        #pragma unroll
        for (int mk = 32; mk >= 1; mk >>= 1) m = fmaxf(m, __shfl_xor(m, mk, 64));
        float e0 = __builtin_amdgcn_exp2f((v0 - m) * L2E);
        float e1 = __builtin_amdgcn_exp2f((v1 - m) * L2E);
        float e2 = __builtin_amdgcn_exp2f((v2 - m) * L2E);
        float e3 = (lane < Sdim - 192) ? __builtin_amdgcn_exp2f((v3 - m) * L2E) : 0.0f;
        float ss = e0 + e1 + e2 + e3;
        #pragma unroll
        for (int mk = 32; mk >= 1; mk >>= 1) ss += __shfl_xor(ss, mk, 64);
        m_max = m; ssum = ss;
    }

    // ---- P3: att_res accumulate; peeled first iter uses prefetched rows ----
    float4 a4 = {0.f, 0.f, 0.f, 0.f};
    {
        float4 sa = *reinterpret_cast<const float4*>(sc + s0);
        float4 sb = *reinterpret_cast<const float4*>(sc + s0 + 4);
        float e0 = __builtin_amdgcn_exp2f((sa.x - m_max) * L2E);
        float e1 = __builtin_amdgcn_exp2f((sa.y - m_max) * L2E);
        float e2 = __builtin_amdgcn_exp2f((sa.z - m_max) * L2E);
        float e3 = __builtin_amdgcn_exp2f((sa.w - m_max) * L2E);
        float e4 = __builtin_amdgcn_exp2f((sb.x - m_max) * L2E);
        float e5 = __builtin_amdgcn_exp2f((sb.y - m_max) * L2E);
        float e6 = __builtin_amdgcn_exp2f((sb.z - m_max) * L2E);
        float e7 = __builtin_amdgcn_exp2f((sb.w - m_max) * L2E);
        a4.x += e0 * av0.x; a4.y += e0 * av0.y; a4.z += e0 * av0.z; a4.w += e0 * av0.w;
        a4.x += e1 * av1.x; a4.y += e1 * av1.y; a4.z += e1 * av1.z; a4.w += e1 * av1.w;
        a4.x += e2 * av2.x; a4.y += e2 * av2.y; a4.z += e2 * av2.z; a4.w += e2 * av2.w;
        a4.x += e3 * av3.x; a4.y += e3 * av3.y; a4.z += e3 * av3.z; a4.w += e3 * av3.w;
        a4.x += e4 * av4.x; a4.y += e4 * av4.y; a4.z += e4 * av4.z; a4.w += e4 * av4.w;
        a4.x += e5 * av5.x; a4.y += e5 * av5.y; a4.z += e5 * av5.z; a4.w += e5 * av5.w;
        a4.x += e6 * av6.x; a4.y += e6 * av6.y; a4.z += e6 * av6.z; a4.w += e6 * av6.w;
        a4.x += e7 * av7.x; a4.y += e7 * av7.y; a4.z += e7 * av7.z; a4.w += e7 * av7.w;
    }
    int s4 = s0 + 8;
    for (; s4 + 8 <= s1; s4 += 8) {
        float4 sa = *reinterpret_cast<const float4*>(sc + s4);
        float4 sb = *reinterpret_cast<const float4*>(sc + s4 + 4);
        float4 v0 = ldnt4(abase + (size_t)(s4 + 0) * Fdim);
        float4 v1 = ldnt4(abase + (size_t)(s4 + 1) * Fdim);
        float4 v2 = ldnt4(abase + (size_t)(s4 + 2) * Fdim);
        float4 v3 = ldnt4(abase + (size_t)(s4 + 3) * Fdim);
        float4 v4 = ldnt4(abase + (size_t)(s4 + 4) * Fdim);
        float4 v5 = ldnt4(abase + (size_t)(s4 + 5) * Fdim);
        float4 v6 = ldnt4(abase + (size_t)(s4 + 6) * Fdim);
        float4 v7 = ldnt4(abase + (size_t)(s4 + 7) * Fdim);
        float e0 = __builtin_amdgcn_exp2f((sa.x - m_max) * L2E);
        float e1 = __builtin_amdgcn_exp2f((sa.y - m_max) * L2E);
        float e2 = __builtin_amdgcn_exp2f((sa.z - m_max) * L2E);
        float e3 = __builtin_amdgcn_exp2f((sa.w - m_max) * L2E);
        float e4 = __builtin_amdgcn_exp2f((sb.x - m_max) * L2E);
        float e5 = __builtin_amdgcn_exp2f((sb.y - m_max) * L2E);
        float e6 = __builtin_amdgcn_exp2f((sb.z - m_max) * L2E);
        float e7 = __builtin_amdgcn_exp2f((sb.w - m_max) * L2E);
        a4.x += e0 * v0.x; a4.y += e0 * v0.y; a4.z += e0 * v0.z; a4.w += e0 * v0.w;
        a4.x += e1 * v1.x; a4.y += e1 * v1.y; a4.z += e1 * v1.z; a4.w += e1 * v1.w;
        a4.x += e2 * v2.x; a4.y += e2 * v2.y; a4.z += e2 * v2.z; a4.w += e2 * v2.w;
        a4.x += e3 * v3.x; a4.y += e3 * v3.y; a4.z += e3 * v3.z; a4.w += e3 * v3.w;
        a4.x += e4 * v4.x; a4.y += e4 * v4.y; a4.z += e4 * v4.z; a4.w += e4 * v4.w;
        a4.x += e5 * v5.x; a4.y += e5 * v5.y; a4.z += e5 * v5.z; a4.w += e5 * v5.w;
        a4.x += e6 * v6.x; a4.y += e6 * v6.y; a4.z += e6 * v6.z; a4.w += e6 * v6.w;
        a4.x += e7 * v7.x; a4.y += e7 * v7.y; a4.z += e7 * v7.z; a4.w += e7 * v7.w;
    }
    if (s4 < s1) {   // tail of 4 (only half 1: s = 192..195)
        float4 sa = *reinterpret_cast<const float4*>(sc + s4);
        float4 v0 = ldnt4(abase + (size_t)(s4 + 0) * Fdim);
        float4 v1 = ldnt4(abase + (size_t)(s4 + 1) * Fdim);
        float4 v2 = ldnt4(abase + (size_t)(s4 + 2) * Fdim);
        float4 v3 = ldnt4(abase + (size_t)(s4 + 3) * Fdim);
        float e0 = __builtin_amdgcn_exp2f((sa.x - m_max) * L2E);
        float e1 = __builtin_amdgcn_exp2f((sa.y - m_max) * L2E);
        float e2 = __builtin_amdgcn_exp2f((sa.z - m_max) * L2E);
        float e3 = __builtin_amdgcn_exp2f((sa.w - m_max) * L2E);
        a4.x += e0 * v0.x; a4.y += e0 * v0.y; a4.z += e0 * v0.z; a4.w += e0 * v0.w;
        a4.x += e1 * v1.x; a4.y += e1 * v1.y; a4.z += e1 * v1.z; a4.w += e1 * v1.w;
        a4.x += e2 * v2.x; a4.y += e2 * v2.y; a4.z += e2 * v2.z; a4.w += e2 * v2.w;
        a4.x += e3 * v3.x; a4.y += e3 * v3.y; a4.z += e3 * v3.z; a4.w += e3 * v3.w;
    }
    if (half) {
        *reinterpret_cast<float4*>(part + fi) = a4;
    }
    __syncthreads();
    if (!half) {
        const float winv = __builtin_amdgcn_rcpf(ssum);
        float4 p4 = *reinterpret_cast<const float4*>(part + fi);
        a4.x = (a4.x + p4.x) * winv; a4.y = (a4.y + p4.y) * winv;
        a4.z = (a4.z + p4.z) * winv; a4.w = (a4.w + p4.w) * winv;
        *reinterpret_cast<float4*>(out + (size_t)b * Fdim + fi) = a4;
    }
}

// ---------------- launch --------------------------------------------------------
extern "C" void kernel_launch(void* const* d_in, const int* in_sizes, int n_in,
                              void* d_out, int out_size, void* d_ws, size_t ws_size,
                              hipStream_t stream) {
    const float* ha       = (const float*)d_in[0];
    const float* hf       = (const float*)d_in[1];
    const float* att_f    = (const float*)d_in[2];
    const float* p_att    = (const float*)d_in[3];
    const float* W_ha     = (const float*)d_in[4];
    const float* b_ha     = (const float*)d_in[5];
    const float* W_hf     = (const float*)d_in[6];
    const float* b_hf     = (const float*)d_in[7];
    const float* w_alpha  = (const float*)d_in[8];
    const float* b_alpha  = (const float*)d_in[9];
    float* out = (float*)d_out;
    __half* qpart = (__half*)d_ws;

    dim3 gA(Hdim / 128, Bdim / 128, KSPLIT);
    gemm_q_mfma<<<gA, 256, 0, stream>>>(ha, hf, W_ha, W_hf, qpart);

    fused_kernel<<<dim3(Bdim), 1024, 0, stream>>>(
        qpart, b_ha, b_hf, p_att, w_alpha, b_alpha, att_f, out, KSPLIT);
}